// Round 21
// baseline (206.165 us; speedup 1.0000x reference)
//
#include <hip/hip_runtime.h>

// ---------------------------------------------------------------------------
// TransformerXL decoder layer on gfx950. bf16 MFMA everywhere matmul-shaped.
// Shapes: QLEN=MLEN=1024, KLEN=2048, BSZ=2, D=1024, H=16, DH=64, DFF=4096.
// Row convention for [len,b,*] tensors: flat row = pos*2 + b (matches jnp).
// R20: extract_vt deleted -- V-transpose fused into the QKV gemm epilogue
//      (V-blocks stash acc into the dead As buffer as a row-XOR-swizzled
//      T[128][128], barrier, coalesced transposed write to Vt). One fewer
//      dispatch + no heads V re-read. Rest = R19 (204.8us).
// ---------------------------------------------------------------------------

typedef unsigned short u16;
typedef unsigned int   u32;
typedef __attribute__((ext_vector_type(8))) short bf16x8;   // MFMA A/B frag
typedef __attribute__((ext_vector_type(4))) float f32x4;    // MFMA C/D frag

struct alignas(16) U128 { u32 x[4]; };
struct alignas(16) F128 { float f[4]; };
struct alignas(8)  U64  { u32 x[2]; };

#define DEV static __device__ __forceinline__
#define MF(a, b, c) __builtin_amdgcn_mfma_f32_16x16x32_bf16((a), (b), (c), 0, 0, 0)

typedef __attribute__((address_space(1))) u32 as1_u32;
typedef __attribute__((address_space(3))) u32 as3_u32;
DEV void gload16(const void* g, void* l) {   // 16B/lane direct global->LDS
  __builtin_amdgcn_global_load_lds((as1_u32*)g, (as3_u32*)l, 16, 0, 0);
}

DEV u16 f2bf(float f) {                      // RNE fp32 -> bf16
  union { float f; u32 u; } v; v.f = f;
  u32 r = v.u + 0x7fffu + ((v.u >> 16) & 1u);
  return (u16)(r >> 16);
}
DEV float bf2f(u16 h) {
  union { u32 u; float f; } v; v.u = ((u32)h) << 16;
  return v.f;
}

// ------- fused: X = p0+p1+p2+p3+resid (f32 out), YN = LN(X) (bf16) --------
__global__ __launch_bounds__(256) void ln_fuse(
    const u16* __restrict__ p0, const u16* __restrict__ p1,
    const u16* __restrict__ p2, const u16* __restrict__ p3,
    const float* __restrict__ resid, const float* __restrict__ g,
    const float* __restrict__ b, float* __restrict__ X, u16* __restrict__ YN)
{
  int row = blockIdx.x, tid = threadIdx.x;
  U64 a = ((const U64*)(p0 + (size_t)row * 1024))[tid];
  U64 c = ((const U64*)(p1 + (size_t)row * 1024))[tid];
  U64 d = ((const U64*)(p2 + (size_t)row * 1024))[tid];
  U64 e = ((const U64*)(p3 + (size_t)row * 1024))[tid];
  F128 rv = ((const F128*)(resid + (size_t)row * 1024))[tid];
  float x[4];
#pragma unroll
  for (int k = 0; k < 2; k++) {
    x[2*k]   = bf2f((u16)a.x[k]) + bf2f((u16)c.x[k]) + bf2f((u16)d.x[k]) + bf2f((u16)e.x[k]) + rv.f[2*k];
    x[2*k+1] = bf2f((u16)(a.x[k] >> 16)) + bf2f((u16)(c.x[k] >> 16)) + bf2f((u16)(d.x[k] >> 16)) + bf2f((u16)(e.x[k] >> 16)) + rv.f[2*k+1];
  }
  F128 xo;
#pragma unroll
  for (int j = 0; j < 4; j++) xo.f[j] = x[j];
  *(F128*)(X + (size_t)row * 1024 + tid * 4) = xo;

  float s = x[0] + x[1] + x[2] + x[3];
  float q = x[0]*x[0] + x[1]*x[1] + x[2]*x[2] + x[3]*x[3];
#pragma unroll
  for (int off = 1; off < 64; off <<= 1) {
    s += __shfl_xor(s, off); q += __shfl_xor(q, off);
  }
  __shared__ float sh[8];
  int wid = tid >> 6;
  if ((tid & 63) == 0) { sh[wid] = s; sh[4 + wid] = q; }
  __syncthreads();
  s = sh[0] + sh[1] + sh[2] + sh[3];
  q = sh[4] + sh[5] + sh[6] + sh[7];
  float mu = s * (1.0f / 1024.0f);
  float rs = rsqrtf(q * (1.0f / 1024.0f) - mu * mu + 1e-5f);
  F128 g4 = ((const F128*)g)[tid];
  F128 b4 = ((const F128*)b)[tid];
  union { u16 h[4]; U64 u; } o;
#pragma unroll
  for (int j = 0; j < 4; j++)
    o.h[j] = f2bf((x[j] - mu) * rs * g4.f[j] + b4.f[j]);
  *(U64*)(YN + (size_t)row * 1024 + tid * 4) = o.u;
}

// -------- fused weight prep + LN1: transposes, pos cvt, ln(mems/input) -----
// ids 0..3327: W[K,N] f32 -> Wt[N,K] bf16, 64x64 tiles.
// ids 3328..5375: pos_emb f32 -> bf16 flat (2048x1024).
// ids 5376..9471: row = id-5376; CATLN[row] = LN(row<2048 ? mems : input).
__global__ __launch_bounds__(256) void prep_weights(
    const float* __restrict__ qkvw, const float* __restrict__ rw,
    const float* __restrict__ oww, const float* __restrict__ fw1,
    const float* __restrict__ fw2, const float* __restrict__ pos,
    const float* __restrict__ mems, const float* __restrict__ input_,
    const float* __restrict__ ln1g, const float* __restrict__ ln1b,
    u16* __restrict__ WT_QKV, u16* __restrict__ WT_R, u16* __restrict__ WT_O,
    u16* __restrict__ WT_F1, u16* __restrict__ WT_F2, u16* __restrict__ POSB,
    u16* __restrict__ CATLN)
{
  int id = blockIdx.x, tid = threadIdx.x;
  if (id >= 5376) {                       // LN1 rows
    int row = id - 5376;
    const float* s_ = (row < 2048) ? mems + (size_t)row * 1024
                                   : input_ + (size_t)(row - 2048) * 1024;
    F128 v = ((const F128*)s_)[tid];
    float s = v.f[0] + v.f[1] + v.f[2] + v.f[3];
    float q = v.f[0]*v.f[0] + v.f[1]*v.f[1] + v.f[2]*v.f[2] + v.f[3]*v.f[3];
#pragma unroll
    for (int off = 1; off < 64; off <<= 1) {
      s += __shfl_xor(s, off); q += __shfl_xor(q, off);
    }
    __shared__ float sh[8];
    int wid = tid >> 6;
    if ((tid & 63) == 0) { sh[wid] = s; sh[4 + wid] = q; }
    __syncthreads();
    s = sh[0] + sh[1] + sh[2] + sh[3];
    q = sh[4] + sh[5] + sh[6] + sh[7];
    float mu = s * (1.0f / 1024.0f);
    float rs = rsqrtf(q * (1.0f / 1024.0f) - mu * mu + 1e-5f);
    F128 g4 = ((const F128*)ln1g)[tid];
    F128 b4 = ((const F128*)ln1b)[tid];
    union { u16 h[4]; U64 u; } o;
#pragma unroll
    for (int j = 0; j < 4; j++)
      o.h[j] = f2bf((v.f[j] - mu) * rs * g4.f[j] + b4.f[j]);
    *(U64*)(CATLN + (size_t)row * 1024 + tid * 4) = o.u;
    return;
  }
  if (id >= 3328) {                       // pos cvt
    int i = (id - 3328) * 256 + tid;
    F128 v = ((const F128*)pos)[i];
    union { u16 h[4]; U64 u; } o;
#pragma unroll
    for (int j = 0; j < 4; j++) o.h[j] = f2bf(v.f[j]);
    ((U64*)POSB)[i] = o.u;
    return;
  }
  const float* W; u16* Wt; int K, N, rem;
  if (id < 768)       { W = qkvw; Wt = WT_QKV; K = 1024; N = 3072; rem = id; }
  else if (id < 1024) { W = rw;   Wt = WT_R;   K = 1024; N = 1024; rem = id - 768; }
  else if (id < 1280) { W = oww;  Wt = WT_O;   K = 1024; N = 1024; rem = id - 1024; }
  else if (id < 2304) { W = fw1;  Wt = WT_F1;  K = 1024; N = 4096; rem = id - 1280; }
  else                { W = fw2;  Wt = WT_F2;  K = 4096; N = 1024; rem = id - 2304; }
  int nn = N >> 6;
  int k0 = (rem / nn) * 64, n0 = (rem % nn) * 64;
  __shared__ float t[64][65];
  int r = tid >> 6, c = tid & 63;
#pragma unroll
  for (int i = 0; i < 16; i++)
    t[r + i * 4][c] = W[(size_t)(k0 + r + i * 4) * N + n0 + c];
  __syncthreads();
#pragma unroll
  for (int i = 0; i < 16; i++) {
    int n = r + i * 4;
    Wt[(size_t)(n0 + n) * K + k0 + c] = f2bf(t[c][n]);
  }
}

// ---------------- GEMM: C[M,N] = A[M,K]*Bt[N,K]^T (+epilogue) --------------
// Double-buffered + T2 both-sides XOR swizzle + T1 XCD block swizzle.
// MAP=0: (m0,n0) from swizzled linear id over the x-y plane.
// MAP=2 (fused QKV+RK+Vt): ids 0..511 QKV K/V cols (n0+=1024), 512..639 QKV
//   Q cols rows 2048+, 640..767 rk (A=p0,B=p1,out=p2). V-blocks (n0>=2048)
//   additionally emit the transposed V tile to Vt (p3) via LDS (replaces the
//   extract_vt kernel).
template <int EPI, int NSPLIT, int MAP = 0>
__global__ __launch_bounds__(256, 2) void gemm_bt(
    const u16* __restrict__ A_, const u16* __restrict__ Bt_,
    u16* __restrict__ outb_, const float* __restrict__ bias_,
    u16* __restrict__ p0, u16* __restrict__ p1,
    u16* __restrict__ p2, u16* __restrict__ p3,
    int M, int N, int K)
{
  __shared__ u16 As[2][128 * 64];
  __shared__ u16 Bs[2][128 * 64];
  int tid = threadIdx.x;
  const u16* A = A_; const u16* Bt = Bt_;
  u16* outb = outb_; const float* bias = bias_;
  int m0, n0, Nst = N;
  bool isV = false;
  if constexpr (MAP == 2) {
    int lid = blockIdx.x;                       // 768 blocks, 768%8==0
    int id = (lid & 7) * 96 + (lid >> 3);       // T1 bijective XCD swizzle
    if (id < 512) { m0 = (id >> 4) * 128; n0 = 1024 + (id & 15) * 128; }
    else if (id < 640) { int i2 = id - 512; m0 = 2048 + (i2 >> 3) * 128; n0 = (i2 & 7) * 128; }
    else {                              // rk: pos @ r_w -> RK
      int i2 = id - 640;
      m0 = (i2 >> 3) * 128; n0 = (i2 & 7) * 128;
      A = p0; Bt = p1; outb = p2; bias = nullptr; Nst = 1024;
    }
    isV = (id < 512) && ((id & 15) >= 8);       // n0 >= 2048 -> V region
  } else {
    int nx = gridDim.x;
    int lid = blockIdx.y * nx + blockIdx.x;     // nwg multiple of 8 (128/512)
    int cpx = (nx * gridDim.y) >> 3;
    int swz = (lid & 7) * cpx + (lid >> 3);     // T1 bijective XCD swizzle
    m0 = (swz % nx) * 128; n0 = (swz / nx) * 128;
  }
  int lane = tid & 63, wid = tid >> 6;
  int wr = wid >> 1, wc = wid & 1;
  f32x4 acc[4][4] = {};

  const int Kc = K / NSPLIT;
  const int kbase = (NSPLIT > 1) ? (int)blockIdx.z * Kc : 0;

  const int lrow = wid * 8 + (lane >> 3);
  const int lcol = 8 * ((lane & 7) ^ (lane >> 3));   // pre-swizzled source col
  const u16* Ag = A  + (size_t)(m0 + lrow) * K + kbase + lcol;
  const u16* Bg = Bt + (size_t)(n0 + lrow) * K + kbase + lcol;

  auto stage = [&](int buf, int k0) {
#pragma unroll
    for (int i = 0; i < 4; i++) {
      gload16(Ag + (size_t)i * 32 * K + k0, &As[buf][(i * 4 + wid) * 512]);
      gload16(Bg + (size_t)i * 32 * K + k0, &Bs[buf][(i * 4 + wid) * 512]);
    }
  };

  const int rswz = 8 * (lane & 7);     // read-side XOR
  stage(0, 0);
  __syncthreads();                    // prologue drain
  int cur = 0;
  for (int k0 = 0; k0 < Kc; k0 += 64) {
    if (k0 + 64 < Kc) stage(cur ^ 1, k0 + 64);
    bf16x8 af[2][4], bfr[2][4];
#pragma unroll
    for (int kc = 0; kc < 2; kc++) {
      int cb = (kc * 32 + (lane >> 4) * 8) ^ rswz;
#pragma unroll
      for (int f = 0; f < 4; f++) {
        af[kc][f]  = *(const bf16x8*)&As[cur][(wr * 64 + f * 16 + (lane & 15)) * 64 + cb];
        bfr[kc][f] = *(const bf16x8*)&Bs[cur][(wc * 64 + f * 16 + (lane & 15)) * 64 + cb];
      }
    }
    __builtin_amdgcn_s_setprio(1);
#pragma unroll
    for (int kc = 0; kc < 2; kc++)
#pragma unroll
      for (int fi = 0; fi < 4; fi++)
#pragma unroll
        for (int fj = 0; fj < 4; fj++)
          acc[fi][fj] = MF(af[kc][fi], bfr[kc][fj], acc[fi][fj]);
    __builtin_amdgcn_s_setprio(0);
    __syncthreads();                  // reads done + next buf staged
    cur ^= 1;
  }

  u16* part = nullptr;
  if constexpr (NSPLIT > 1) {
    part = (blockIdx.z == 0) ? p0 : (blockIdx.z == 1) ? p1
         : (blockIdx.z == 2) ? p2 : p3;
  }
  u16* T = (u16*)&As[0][0];            // 32KB, dead after main loop: T[128][128]
#pragma unroll
  for (int fi = 0; fi < 4; fi++)
#pragma unroll
    for (int fj = 0; fj < 4; fj++) {
      int col = n0 + wc * 64 + fj * 16 + (lane & 15);
      float bvv = (NSPLIT == 1 && bias != nullptr) ? bias[col] : 0.0f;
#pragma unroll
      for (int r = 0; r < 4; r++) {
        int row = m0 + wr * 64 + fi * 16 + (lane >> 4) * 4 + r;
        float v = acc[fi][fj][r] + bvv;
        if constexpr (NSPLIT > 1) {
          part[(size_t)row * Nst + col] = f2bf(v);
        } else {
          if constexpr (EPI == 1) v = fmaxf(v, 0.0f);
          outb[(size_t)row * Nst + col] = f2bf(v);
          if constexpr (MAP == 2) {
            if (isV) {                 // stash into swizzled T for Vt emit
              int rr  = wr * 64 + fi * 16 + (lane >> 4) * 4 + r;
              int cc2 = wc * 64 + fj * 16 + (lane & 15);
              T[rr * 128 + (cc2 ^ ((rr & 15) << 3))] = f2bf(v);
            }
          }
        }
      }
    }

  if constexpr (MAP == 2) {
    if (isV) {                         // block-uniform -> barrier legal
      __syncthreads();
      int cl = tid & 127, bb = tid >> 7;         // cl = col in tile, bb = batch
      int h = ((n0 - 2048) >> 6) + (cl >> 6);
      int d = cl & 63;
      u16* dst = p3 + (((size_t)(bb * 16 + h) * 64 + d) * 2048) + (m0 >> 1);
#pragma unroll
      for (int q = 0; q < 16; q++) {
        U64 oo;
        u16* h4 = (u16*)&oo;
#pragma unroll
        for (int jl = 0; jl < 4; jl++) {
          int rr = 8 * q + 2 * jl + bb;          // flat row = j*2 + b
          h4[jl] = T[rr * 128 + (cl ^ ((rr & 15) << 3))];
        }
        *(U64*)(dst + 4 * q) = oo;
      }
    }
  }
}

// ---------------- split-K reduce (bf16 partials) ---------------------------
template <int NS, int EPI>
__global__ __launch_bounds__(256) void reduce_splitb(
    const u16* __restrict__ p0, const u16* __restrict__ p1,
    const u16* __restrict__ p2, const u16* __restrict__ p3,
    const float* __restrict__ bias, const float* __restrict__ resid,
    u16* __restrict__ outb, float* __restrict__ outf, int N)
{
  int e = (blockIdx.x * 256 + threadIdx.x) * 8;
  U128 a = *(const U128*)(p0 + e);
  U128 c = *(const U128*)(p1 + e);
  float v[8];
#pragma unroll
  for (int k = 0; k < 4; k++) {
    v[2*k]   = bf2f((u16)a.x[k]) + bf2f((u16)c.x[k]);
    v[2*k+1] = bf2f((u16)(a.x[k] >> 16)) + bf2f((u16)(c.x[k] >> 16));
  }
  if constexpr (NS == 4) {
    U128 d2 = *(const U128*)(p2 + e);
    U128 d3 = *(const U128*)(p3 + e);
#pragma unroll
    for (int k = 0; k < 4; k++) {
      v[2*k]   += bf2f((u16)d2.x[k]) + bf2f((u16)d3.x[k]);
      v[2*k+1] += bf2f((u16)(d2.x[k] >> 16)) + bf2f((u16)(d3.x[k] >> 16));
    }
  }
  if constexpr (EPI == 2) {
    F128 r0 = *(const F128*)(resid + e);
    F128 r1 = *(const F128*)(resid + e + 4);
    int col = e % N;
    F128 o0, o1;
#pragma unroll
    for (int j = 0; j < 4; j++) {
      float b0 = (bias != nullptr) ? bias[col + j] : 0.0f;
      float b1 = (bias != nullptr) ? bias[col + 4 + j] : 0.0f;
      o0.f[j] = v[j] + b0 + r0.f[j];
      o1.f[j] = v[4 + j] + b1 + r1.f[j];
    }
    *(F128*)(outf + e) = o0;
    *(F128*)(outf + e + 4) = o1;
  } else {
    U128 o;
#pragma unroll
    for (int k = 0; k < 4; k++)
      o.x[k] = (u32)f2bf(v[2*k]) | ((u32)f2bf(v[2*k+1]) << 16);
    *(U128*)(outb + e) = o;
  }
}

// ---------------- fused rel-attention (flash-style) ------------------------
// VERBATIM R11 kernel (70.4us, best-measured thrice). Do not touch: rt[]
// arrays trigger PromoteAlloca->LDS; inline-asm cvt_pk defeats scheduling;
// 20-shfl variant measured noise-neutral (R17).
__global__ __launch_bounds__(256, 2) void attn_fwd(
    const u16* __restrict__ heads, const u16* __restrict__ rk,
    const u16* __restrict__ Vt, const float* __restrict__ rwb,
    const float* __restrict__ rrb, u16* __restrict__ attnout)
{
  // layout (u16): buf b at b*16384: K @+0 (4096), V @+4096 (4096), R @+8192 (8192)
  // Ps @32768 (64x72). Q overlay @0 during init (Qw 64x72, Qr at +4608).
  __shared__ u16 lds[37376];

  int tid = threadIdx.x, lane = tid & 63, wid = tid >> 6;
  int bh = blockIdx.x;                  // bh%8 -> XCD: blocks sharing K/V co-locate
  int y = (int)blockIdx.y;
  int xt = (y < 8) ? y : 23 - y;        // CU pairing: work(y)+work(y+8) = 49 tiles
  int i0 = xt * 64;
  int b = bh >> 4, h = bh & 15;
  const float SCL = 0.18033688f;        // 0.125 * log2(e)

  u16* Ps = lds + 32768;
  u16* Qw = lds;                        // overlay during init
  u16* Qr = lds + 4608;

  // ---- Q staging (overlay; f32 bias add, bf16 store) ----
  for (int c = tid; c < 512; c += 256) {
    int row = c >> 3, c8 = (c & 7) * 8;
    union { U128 v; u16 h[8]; } in, ow, orr;
    in.v = *(const U128*)&heads[(size_t)((1024 + i0 + row) * 2 + b) * 3072 + h * 64 + c8];
#pragma unroll
    for (int j = 0; j < 8; j++) {
      float q = bf2f(in.h[j]);
      ow.h[j]  = f2bf(q + rwb[h * 64 + c8 + j]);
      orr.h[j] = f2bf(q + rrb[h * 64 + c8 + j]);
    }
    *(U128*)&Qw[row * 72 + c8] = ow.v;
    *(U128*)&Qr[row * 72 + c8] = orr.v;
  }
  __syncthreads();

  bf16x8 qwf[2], qrf[2];
  int qrow = wid * 16 + (lane & 15);
#pragma unroll
  for (int kc = 0; kc < 2; kc++) {
    qwf[kc] = *(const bf16x8*)&Qw[qrow * 72 + kc * 32 + (lane >> 4) * 8];
    qrf[kc] = *(const bf16x8*)&Qr[qrow * 72 + kc * 32 + (lane >> 4) * 8];
  }
  __syncthreads();                 // overlay reads done before gload overwrites

  // ---- staging (global_load_lds, source-side XOR swizzle) ----
  const int srow = lane >> 3;                    // row within 8-row group
  const int scol = 8 * ((lane & 7) ^ srow);      // pre-swizzled source col (u16)

  auto stage = [&](int buf, int t) {
    int j0 = t * 64;
    u16* base = lds + buf * 16384;
#pragma unroll
    for (int i = 0; i < 2; i++) {               // K: rows g8*8+srow
      int g8 = wid * 2 + i;
      int jr = j0 + g8 * 8 + srow;
      gload16(heads + (size_t)(jr * 2 + b) * 3072 + 1024 + h * 64 + scol,
              base + g8 * 512);
    }
#pragma unroll
    for (int i = 0; i < 2; i++) {               // V^T: rows = d
      int g8 = wid * 2 + i;
      int dr = g8 * 8 + srow;
      gload16(Vt + ((size_t)bh * 64 + dr) * 2048 + j0 + scol,
              base + 4096 + g8 * 512);
    }
    int rbase = 960 + j0 - i0;                  // R band (clamped rows masked)
#pragma unroll
    for (int i = 0; i < 4; i++) {
      int g8 = wid * 4 + i;
      int rr = rbase + g8 * 8 + srow;
      rr = rr < 0 ? 0 : (rr > 2047 ? 2047 : rr);
      gload16(rk + (size_t)rr * 1024 + h * 64 + scol,
              base + 8192 + g8 * 512);
    }
  };

  stage(0, 0);
  __syncthreads();                 // tile 0 staged

  float mrow[4], plrow[4];
  f32x4 o[4] = {};
  f32x4 bd[5];
#pragma unroll
  for (int r = 0; r < 4; r++) { mrow[r] = -1e30f; plrow[r] = 0.0f; }

  int nt = i0 / 64 + 17;           // covers j <= i0+63+1024
  const int roffw = 48 - wid * 16;
  const int g = lane >> 4, cc = lane & 15;
  const int rswz = 8 * (lane & 7); // read-side XOR (row&7 == lane&7 for all frags)

  for (int t = 0; t < nt; t++) {
    const u16* base = lds + (t & 1) * 16384;
    if (t + 1 < nt) stage((t + 1) & 1, t + 1);  // overlaps compute below

    const u16* Kb = base;
    const u16* Vb = base + 4096;
    const u16* Rb = base + 8192;

    // AC = Qw.K^T ; BD band frags (fb=0 carried from prev tile, d-window +64)
    f32x4 sAC[4] = {};
    if (t == 0) bd[0] = (f32x4){0.f, 0.f, 0.f, 0.f};
#pragma unroll
    for (int fb = 1; fb < 5; fb++) bd[fb] = (f32x4){0.f, 0.f, 0.f, 0.f};
    __builtin_amdgcn_s_setprio(1);
#pragma unroll
    for (int kc = 0; kc < 2; kc++) {
      int cb = (kc * 32 + g * 8) ^ rswz;
#pragma unroll
      for (int fj = 0; fj < 4; fj++) {
        bf16x8 kf = *(const bf16x8*)&Kb[(fj * 16 + (lane & 15)) * 64 + cb];
        sAC[fj] = MF(qwf[kc], kf, sAC[fj]);
      }
      if (t == 0) {
        bf16x8 rf = *(const bf16x8*)&Rb[(roffw + (lane & 15)) * 64 + cb];
        bd[0] = MF(qrf[kc], rf, bd[0]);
      }
#pragma unroll
      for (int fb = 1; fb < 5; fb++) {
        bf16x8 rf = *(const bf16x8*)&Rb[(roffw + fb * 16 + (lane & 15)) * 64 + cb];
        bd[fb] = MF(qrf[kc], rf, bd[fb]);
      }
    }
    __builtin_amdgcn_s_setprio(0);

    // merge AC + diagonal-gathered BD (log2 domain)
    float p[4][4];
#pragma unroll
    for (int fj = 0; fj < 4; fj++)
#pragma unroll
      for (int r = 0; r < 4; r++) {
        int sh_ = 15 - 4 * g - r;                    // uniform per (quarter, r)
        int src = (lane & 48) | ((lane + sh_) & 15);
        float lo = __shfl(bd[fj][r], src);
        float hi = __shfl(bd[fj + 1][r], src);
        float bdv = (cc + sh_ < 16) ? lo : hi;
        p[fj][r] = (sAC[fj][r] + bdv) * SCL;
      }
    bd[0] = bd[4];                 // carry: next tile's fb=0 window

    if (t == nt - 1) {             // only the last tile has masked entries
#pragma unroll
      for (int fj = 0; fj < 4; fj++)
#pragma unroll
        for (int r = 0; r < 4; r++)
          if (fj * 16 + cc > 16 * wid + 4 * g + r) p[fj][r] = -1e30f;
    }

    float tmax[4];
#pragma unroll
    for (int r = 0; r < 4; r++)
      tmax[r] = fmaxf(fmaxf(p[0][r], p[1][r]), fmaxf(p[2][r], p[3][r]));

    bool ok = true;
#pragma unroll
    for (int r = 0; r < 4; r++) ok &= (tmax[r] <= mrow[r] + 12.0f);
    if (!__all(ok)) {              // rare: true max moved too far -> rescale
#pragma unroll
      for (int off = 1; off < 16; off <<= 1)
#pragma unroll
        for (int r = 0; r < 4; r++)
          tmax[r] = fmaxf(tmax[r], __shfl_xor(tmax[r], off));
#pragma unroll
      for (int r = 0; r < 4; r++) {
        float mn = fmaxf(mrow[r], tmax[r]);
        float ms = exp2f(mrow[r] - mn);
        mrow[r] = mn;
        plrow[r] *= ms;
#pragma unroll
        for (int fd = 0; fd < 4; fd++) o[fd][r] *= ms;
      }
    }

    // P = 2^(p-m) (bounded by 2^12), per-lane l partial, P -> LDS
#pragma unroll
    for (int fj = 0; fj < 4; fj++)
#pragma unroll
      for (int r = 0; r < 4; r++) {
        float e = exp2f(p[fj][r] - mrow[r]);
        plrow[r] += e;
        Ps[(wid * 16 + (lane >> 4) * 4 + r) * 72 + fj * 16 + (lane & 15)] = f2bf(e);
      }
    __builtin_amdgcn_s_setprio(1);
#pragma unroll
    for (int kc = 0; kc < 2; kc++) {
      bf16x8 pf = *(const bf16x8*)&Ps[(wid * 16 + (lane & 15)) * 72 + kc * 32 + g * 8];
      int cb = (kc * 32 + g * 8) ^ rswz;
#pragma unroll
      for (int fd = 0; fd < 4; fd++) {
        bf16x8 vf = *(const bf16x8*)&Vb[(fd * 16 + (lane & 15)) * 64 + cb];
        o[fd] = MF(pf, vf, o[fd]);
      }
    }
    __builtin_amdgcn_s_setprio(0);

    __syncthreads();               // drains stage(t+1) + protects buf reuse
  }

  // epilogue: single deferred l reduction (16-lane groups), then divide
#pragma unroll
  for (int off = 1; off < 16; off <<= 1)
#pragma unroll
    for (int r = 0; r < 4; r++)
      plrow[r] += __shfl_xor(plrow[r], off);
#pragma unroll
  for (int fd = 0; fd < 4; fd++)
#pragma unroll
    for (int r = 0; r < 4; r++) {
      int ii2 = (lane >> 4) * 4 + r;
      int row = (i0 + wid * 16 + ii2) * 2 + b;
      attnout[(size_t)row * 1024 + h * 64 + fd * 16 + (lane & 15)] = f2bf(o[fd][r] / plrow[r]);
    }
}

// ---------------------------------------------------------------------------
extern "C" void kernel_launch(void* const* d_in, const int* in_sizes, int n_in,
                              void* d_out, int out_size, void* d_ws, size_t ws_size,
                              hipStream_t stream)
{
  const float* input_ = (const float*)d_in[0];
  const float* mems   = (const float*)d_in[1];
  const float* pos    = (const float*)d_in[2];
  // d_in[3] = mask_tgt: analytic (j > i + 1024), never read
  const float* ln1g = (const float*)d_in[4];
  const float* ln1b = (const float*)d_in[5];
  const float* qkvw = (const float*)d_in[6];
  const float* qkvb = (const float*)d_in[7];
  const float* rw   = (const float*)d_in[8];
  const float* rwb  = (const float*)d_in[9];
  const float* rrb  = (const float*)d_in[10];
  const float* ow   = (const float*)d_in[11];
  const float* ln2g = (const float*)d_in[12];
  const float* ln2b = (const float*)d_in[13];
  const float* fw1  = (const float*)d_in[14];
  const float* fb1  = (const float*)d_in[15];
  const float* fw2  = (const float*)d_in[16];
  const float* fb2  = (const float*)d_in[17];
  float* out = (float*)d_out;

  char* w = (char*)d_ws;
  u16* WT_QKV = (u16*)(w + 0);          // [3072,1024] bf16   6291456
  u16* WT_R   = (u16*)(w + 6291456);    // [1024,1024]        2097152
  u16* WT_O   = (u16*)(w + 8388608);    // [1024,1024]        2097152
  u16* WT_F1  = (u16*)(w + 10485760);   // [4096,1024]        8388608
  u16* WT_F2  = (u16*)(w + 18874368);   // [1024,4096]        8388608
  u16* POSB   = (u16*)(w + 27262976);   // [2048,1024]        4194304
  u16* ATTN   = POSB;                   // alias: POSB dead after fused QKV+rk
  u16* CATLN  = (u16*)(w + 31457280);   // [4096,1024]        8388608
  u16* HEADS  = (u16*)(w + 39845888);   // [4096,3072]        25165824
  u16* H1     = HEADS;                  // alias: heads dead when F1 gemm runs
  float* X    = (float*)(w + 56623104); // [2048,1024] f32    8388608 (heads tail; live after attn)
  u16* RK     = (u16*)(w + 65011712);   // [2048,1024]        4194304
  u16* VT     = (u16*)(w + 69206016);   // [2,16,64,2048]     8388608
  u16* YN     = VT;                     // alias: VT dead after attention

  // bf16 split-K partials (each 2048x1024 u16 = 4194304 B) in dead regions
  u16* OWP0 = (u16*)(w + 39845888);     // = HEADS (dead after attn)
  u16* OWP1 = (u16*)(w + 44040192);
  u16* OWP2 = (u16*)(w + 48234496);
  u16* OWP3 = (u16*)(w + 52428800);     // ends at 56623104 = X (ln_fuse reads before F1 writes H1)
  u16* F2P0 = (u16*)(w + 0);            // = WT_QKV head (dead)
  u16* F2P1 = (u16*)(w + 10485760);     // = WT_F1 (dead after f1 gemm)
  u16* F2P2 = (u16*)(w + 31457280);     // = CATLN (dead)
  u16* F2P3 = (u16*)(w + 65011712);     // = RK (dead after attn)

  dim3 blk(256);

  // fused weight prep + LN1: 5 transposes + pos cvt + 4096 LN rows, ONE launch
  prep_weights<<<dim3(9472), blk, 0, stream>>>(
      qkvw, rw, ow, fw1, fw2, pos, mems, input_, ln1g, ln1b,
      WT_QKV, WT_R, WT_O, WT_F1, WT_F2, POSB, CATLN);

  // fused: heads = catln @ qkv_w + qkv_b (live blocks) + rk = pos @ r_w
  //        + Vt transpose emitted from V-blocks (p3 = VT)
  gemm_bt<0, 1, 2><<<dim3(768), blk, 0, stream>>>(
      CATLN, WT_QKV, HEADS, qkvb, POSB, WT_R, RK, VT, 4096, 3072, 1024);

  attn_fwd<<<dim3(32, 16), blk, 0, stream>>>(HEADS, RK, VT, rwb, rrb, ATTN);

  // X = input + attn @ o_w  (split-K 4) ; YN = LN(X) fused into the reduce
  gemm_bt<0, 4><<<dim3(16, 8, 4), blk, 0, stream>>>(
      ATTN, WT_O, nullptr, nullptr, OWP0, OWP1, OWP2, OWP3, 2048, 1024, 1024);
  ln_fuse<<<dim3(2048), blk, 0, stream>>>(
      OWP0, OWP1, OWP2, OWP3, input_, ln2g, ln2b, X, YN);

  // FFN: out = X + relu(LN(X) @ w1 + b1) @ w2 + b2
  gemm_bt<1, 1><<<dim3(16, 32), blk, 0, stream>>>(
      YN, WT_F1, H1, fb1, nullptr, nullptr, nullptr, nullptr, 2048, 4096, 1024);
  gemm_bt<0, 4><<<dim3(16, 8, 4), blk, 0, stream>>>(
      H1, WT_F2, nullptr, nullptr, F2P0, F2P1, F2P2, F2P3, 2048, 1024, 4096);
  reduce_splitb<4, 2><<<dim3(1024), blk, 0, stream>>>(
      F2P0, F2P1, F2P2, F2P3, fb2, X, nullptr, out, 1024);
}

// Round 22
// 204.420 us; speedup vs baseline: 1.0085x; 1.0085x over previous
//
#include <hip/hip_runtime.h>

// ---------------------------------------------------------------------------
// TransformerXL decoder layer on gfx950. bf16 MFMA everywhere matmul-shaped.
// Shapes: QLEN=MLEN=1024, KLEN=2048, BSZ=2, D=1024, H=16, DH=64, DFF=4096.
// Row convention for [len,b,*] tensors: flat row = pos*2 + b (matches jnp).
// R21: REVERT to R19 verbatim (204.8us, best measured). R20's Vt-fusion was
//      -1.4us (epilogue transpose ran in the QKV dispatch tail). Final
//      structure: prep+LN1 fused launch; QKV+rk fused MFMA launch (T1+T2
//      swizzles); R11 attn (70.4us, 6x-reproduced); ow split-K4 + ln_fuse;
//      f1; f2 split-K4 + reduce.
// ---------------------------------------------------------------------------

typedef unsigned short u16;
typedef unsigned int   u32;
typedef __attribute__((ext_vector_type(8))) short bf16x8;   // MFMA A/B frag
typedef __attribute__((ext_vector_type(4))) float f32x4;    // MFMA C/D frag

struct alignas(16) U128 { u32 x[4]; };
struct alignas(16) F128 { float f[4]; };
struct alignas(8)  U64  { u32 x[2]; };

#define DEV static __device__ __forceinline__
#define MF(a, b, c) __builtin_amdgcn_mfma_f32_16x16x32_bf16((a), (b), (c), 0, 0, 0)

typedef __attribute__((address_space(1))) u32 as1_u32;
typedef __attribute__((address_space(3))) u32 as3_u32;
DEV void gload16(const void* g, void* l) {   // 16B/lane direct global->LDS
  __builtin_amdgcn_global_load_lds((as1_u32*)g, (as3_u32*)l, 16, 0, 0);
}

DEV u16 f2bf(float f) {                      // RNE fp32 -> bf16
  union { float f; u32 u; } v; v.f = f;
  u32 r = v.u + 0x7fffu + ((v.u >> 16) & 1u);
  return (u16)(r >> 16);
}
DEV float bf2f(u16 h) {
  union { u32 u; float f; } v; v.u = ((u32)h) << 16;
  return v.f;
}

// ------- fused: X = p0+p1+p2+p3+resid (f32 out), YN = LN(X) (bf16) --------
__global__ __launch_bounds__(256) void ln_fuse(
    const u16* __restrict__ p0, const u16* __restrict__ p1,
    const u16* __restrict__ p2, const u16* __restrict__ p3,
    const float* __restrict__ resid, const float* __restrict__ g,
    const float* __restrict__ b, float* __restrict__ X, u16* __restrict__ YN)
{
  int row = blockIdx.x, tid = threadIdx.x;
  U64 a = ((const U64*)(p0 + (size_t)row * 1024))[tid];
  U64 c = ((const U64*)(p1 + (size_t)row * 1024))[tid];
  U64 d = ((const U64*)(p2 + (size_t)row * 1024))[tid];
  U64 e = ((const U64*)(p3 + (size_t)row * 1024))[tid];
  F128 rv = ((const F128*)(resid + (size_t)row * 1024))[tid];
  float x[4];
#pragma unroll
  for (int k = 0; k < 2; k++) {
    x[2*k]   = bf2f((u16)a.x[k]) + bf2f((u16)c.x[k]) + bf2f((u16)d.x[k]) + bf2f((u16)e.x[k]) + rv.f[2*k];
    x[2*k+1] = bf2f((u16)(a.x[k] >> 16)) + bf2f((u16)(c.x[k] >> 16)) + bf2f((u16)(d.x[k] >> 16)) + bf2f((u16)(e.x[k] >> 16)) + rv.f[2*k+1];
  }
  F128 xo;
#pragma unroll
  for (int j = 0; j < 4; j++) xo.f[j] = x[j];
  *(F128*)(X + (size_t)row * 1024 + tid * 4) = xo;

  float s = x[0] + x[1] + x[2] + x[3];
  float q = x[0]*x[0] + x[1]*x[1] + x[2]*x[2] + x[3]*x[3];
#pragma unroll
  for (int off = 1; off < 64; off <<= 1) {
    s += __shfl_xor(s, off); q += __shfl_xor(q, off);
  }
  __shared__ float sh[8];
  int wid = tid >> 6;
  if ((tid & 63) == 0) { sh[wid] = s; sh[4 + wid] = q; }
  __syncthreads();
  s = sh[0] + sh[1] + sh[2] + sh[3];
  q = sh[4] + sh[5] + sh[6] + sh[7];
  float mu = s * (1.0f / 1024.0f);
  float rs = rsqrtf(q * (1.0f / 1024.0f) - mu * mu + 1e-5f);
  F128 g4 = ((const F128*)g)[tid];
  F128 b4 = ((const F128*)b)[tid];
  union { u16 h[4]; U64 u; } o;
#pragma unroll
  for (int j = 0; j < 4; j++)
    o.h[j] = f2bf((x[j] - mu) * rs * g4.f[j] + b4.f[j]);
  *(U64*)(YN + (size_t)row * 1024 + tid * 4) = o.u;
}

// -------- fused weight prep + LN1: transposes, pos cvt, ln(mems/input) -----
// ids 0..3327: W[K,N] f32 -> Wt[N,K] bf16, 64x64 tiles.
// ids 3328..5375: pos_emb f32 -> bf16 flat (2048x1024).
// ids 5376..9471: row = id-5376; CATLN[row] = LN(row<2048 ? mems : input).
__global__ __launch_bounds__(256) void prep_weights(
    const float* __restrict__ qkvw, const float* __restrict__ rw,
    const float* __restrict__ oww, const float* __restrict__ fw1,
    const float* __restrict__ fw2, const float* __restrict__ pos,
    const float* __restrict__ mems, const float* __restrict__ input_,
    const float* __restrict__ ln1g, const float* __restrict__ ln1b,
    u16* __restrict__ WT_QKV, u16* __restrict__ WT_R, u16* __restrict__ WT_O,
    u16* __restrict__ WT_F1, u16* __restrict__ WT_F2, u16* __restrict__ POSB,
    u16* __restrict__ CATLN)
{
  int id = blockIdx.x, tid = threadIdx.x;
  if (id >= 5376) {                       // LN1 rows
    int row = id - 5376;
    const float* s_ = (row < 2048) ? mems + (size_t)row * 1024
                                   : input_ + (size_t)(row - 2048) * 1024;
    F128 v = ((const F128*)s_)[tid];
    float s = v.f[0] + v.f[1] + v.f[2] + v.f[3];
    float q = v.f[0]*v.f[0] + v.f[1]*v.f[1] + v.f[2]*v.f[2] + v.f[3]*v.f[3];
#pragma unroll
    for (int off = 1; off < 64; off <<= 1) {
      s += __shfl_xor(s, off); q += __shfl_xor(q, off);
    }
    __shared__ float sh[8];
    int wid = tid >> 6;
    if ((tid & 63) == 0) { sh[wid] = s; sh[4 + wid] = q; }
    __syncthreads();
    s = sh[0] + sh[1] + sh[2] + sh[3];
    q = sh[4] + sh[5] + sh[6] + sh[7];
    float mu = s * (1.0f / 1024.0f);
    float rs = rsqrtf(q * (1.0f / 1024.0f) - mu * mu + 1e-5f);
    F128 g4 = ((const F128*)ln1g)[tid];
    F128 b4 = ((const F128*)ln1b)[tid];
    union { u16 h[4]; U64 u; } o;
#pragma unroll
    for (int j = 0; j < 4; j++)
      o.h[j] = f2bf((v.f[j] - mu) * rs * g4.f[j] + b4.f[j]);
    *(U64*)(CATLN + (size_t)row * 1024 + tid * 4) = o.u;
    return;
  }
  if (id >= 3328) {                       // pos cvt
    int i = (id - 3328) * 256 + tid;
    F128 v = ((const F128*)pos)[i];
    union { u16 h[4]; U64 u; } o;
#pragma unroll
    for (int j = 0; j < 4; j++) o.h[j] = f2bf(v.f[j]);
    ((U64*)POSB)[i] = o.u;
    return;
  }
  const float* W; u16* Wt; int K, N, rem;
  if (id < 768)       { W = qkvw; Wt = WT_QKV; K = 1024; N = 3072; rem = id; }
  else if (id < 1024) { W = rw;   Wt = WT_R;   K = 1024; N = 1024; rem = id - 768; }
  else if (id < 1280) { W = oww;  Wt = WT_O;   K = 1024; N = 1024; rem = id - 1024; }
  else if (id < 2304) { W = fw1;  Wt = WT_F1;  K = 1024; N = 4096; rem = id - 1280; }
  else                { W = fw2;  Wt = WT_F2;  K = 4096; N = 1024; rem = id - 2304; }
  int nn = N >> 6;
  int k0 = (rem / nn) * 64, n0 = (rem % nn) * 64;
  __shared__ float t[64][65];
  int r = tid >> 6, c = tid & 63;
#pragma unroll
  for (int i = 0; i < 16; i++)
    t[r + i * 4][c] = W[(size_t)(k0 + r + i * 4) * N + n0 + c];
  __syncthreads();
#pragma unroll
  for (int i = 0; i < 16; i++) {
    int n = r + i * 4;
    Wt[(size_t)(n0 + n) * K + k0 + c] = f2bf(t[c][n]);
  }
}

// ---------------- GEMM: C[M,N] = A[M,K]*Bt[N,K]^T (+epilogue) --------------
// Double-buffered + T2 both-sides XOR swizzle (conflict-free frag reads).
// T1 XCD swizzle on block ids (all grids are multiples of 8 -> bijective).
// MAP=0: (m0,n0) from swizzled linear id over the x-y plane.
// MAP=2 (fused QKV+RK): swizzled linear blockIdx.x; ids 0..511 -> QKV K/V
//   cols (n0 += 1024, all rows), 512..639 -> QKV Q cols rows 2048+, 640..767
//   -> rk problem: A=p0,B=p1,out=p2, N=1024, same K, no bias.
template <int EPI, int NSPLIT, int MAP = 0>
__global__ __launch_bounds__(256, 2) void gemm_bt(
    const u16* __restrict__ A_, const u16* __restrict__ Bt_,
    u16* __restrict__ outb_, const float* __restrict__ bias_,
    u16* __restrict__ p0, u16* __restrict__ p1,
    u16* __restrict__ p2, u16* __restrict__ p3,
    int M, int N, int K)
{
  __shared__ u16 As[2][128 * 64];
  __shared__ u16 Bs[2][128 * 64];
  int tid = threadIdx.x;
  const u16* A = A_; const u16* Bt = Bt_;
  u16* outb = outb_; const float* bias = bias_;
  int m0, n0, Nst = N;
  if constexpr (MAP == 2) {
    int lid = blockIdx.x;                       // 768 blocks, 768%8==0
    int id = (lid & 7) * 96 + (lid >> 3);       // T1 bijective XCD swizzle
    if (id < 512) { m0 = (id >> 4) * 128; n0 = 1024 + (id & 15) * 128; }
    else if (id < 640) { int i2 = id - 512; m0 = 2048 + (i2 >> 3) * 128; n0 = (i2 & 7) * 128; }
    else {                              // rk: pos @ r_w -> RK
      int i2 = id - 640;
      m0 = (i2 >> 3) * 128; n0 = (i2 & 7) * 128;
      A = p0; Bt = p1; outb = p2; bias = nullptr; Nst = 1024;
    }
  } else {
    int nx = gridDim.x;
    int lid = blockIdx.y * nx + blockIdx.x;     // nwg multiple of 8 (128/512)
    int cpx = (nx * gridDim.y) >> 3;
    int swz = (lid & 7) * cpx + (lid >> 3);     // T1 bijective XCD swizzle
    m0 = (swz % nx) * 128; n0 = (swz / nx) * 128;
  }
  int lane = tid & 63, wid = tid >> 6;
  int wr = wid >> 1, wc = wid & 1;
  f32x4 acc[4][4] = {};

  const int Kc = K / NSPLIT;
  const int kbase = (NSPLIT > 1) ? (int)blockIdx.z * Kc : 0;

  const int lrow = wid * 8 + (lane >> 3);
  const int lcol = 8 * ((lane & 7) ^ (lane >> 3));   // pre-swizzled source col
  const u16* Ag = A  + (size_t)(m0 + lrow) * K + kbase + lcol;
  const u16* Bg = Bt + (size_t)(n0 + lrow) * K + kbase + lcol;

  auto stage = [&](int buf, int k0) {
#pragma unroll
    for (int i = 0; i < 4; i++) {
      gload16(Ag + (size_t)i * 32 * K + k0, &As[buf][(i * 4 + wid) * 512]);
      gload16(Bg + (size_t)i * 32 * K + k0, &Bs[buf][(i * 4 + wid) * 512]);
    }
  };

  const int rswz = 8 * (lane & 7);     // read-side XOR
  stage(0, 0);
  __syncthreads();                    // prologue drain
  int cur = 0;
  for (int k0 = 0; k0 < Kc; k0 += 64) {
    if (k0 + 64 < Kc) stage(cur ^ 1, k0 + 64);
    bf16x8 af[2][4], bfr[2][4];
#pragma unroll
    for (int kc = 0; kc < 2; kc++) {
      int cb = (kc * 32 + (lane >> 4) * 8) ^ rswz;
#pragma unroll
      for (int f = 0; f < 4; f++) {
        af[kc][f]  = *(const bf16x8*)&As[cur][(wr * 64 + f * 16 + (lane & 15)) * 64 + cb];
        bfr[kc][f] = *(const bf16x8*)&Bs[cur][(wc * 64 + f * 16 + (lane & 15)) * 64 + cb];
      }
    }
    __builtin_amdgcn_s_setprio(1);
#pragma unroll
    for (int kc = 0; kc < 2; kc++)
#pragma unroll
      for (int fi = 0; fi < 4; fi++)
#pragma unroll
        for (int fj = 0; fj < 4; fj++)
          acc[fi][fj] = MF(af[kc][fi], bfr[kc][fj], acc[fi][fj]);
    __builtin_amdgcn_s_setprio(0);
    __syncthreads();                  // reads done + next buf staged
    cur ^= 1;
  }

  u16* part = nullptr;
  if constexpr (NSPLIT > 1) {
    part = (blockIdx.z == 0) ? p0 : (blockIdx.z == 1) ? p1
         : (blockIdx.z == 2) ? p2 : p3;
  }
#pragma unroll
  for (int fi = 0; fi < 4; fi++)
#pragma unroll
    for (int fj = 0; fj < 4; fj++) {
      int col = n0 + wc * 64 + fj * 16 + (lane & 15);
      float bvv = (NSPLIT == 1 && bias != nullptr) ? bias[col] : 0.0f;
#pragma unroll
      for (int r = 0; r < 4; r++) {
        int row = m0 + wr * 64 + fi * 16 + (lane >> 4) * 4 + r;
        float v = acc[fi][fj][r] + bvv;
        if constexpr (NSPLIT > 1) {
          part[(size_t)row * Nst + col] = f2bf(v);
        } else {
          if constexpr (EPI == 1) v = fmaxf(v, 0.0f);
          outb[(size_t)row * Nst + col] = f2bf(v);
        }
      }
    }
}

// ---------------- split-K reduce (bf16 partials) ---------------------------
template <int NS, int EPI>
__global__ __launch_bounds__(256) void reduce_splitb(
    const u16* __restrict__ p0, const u16* __restrict__ p1,
    const u16* __restrict__ p2, const u16* __restrict__ p3,
    const float* __restrict__ bias, const float* __restrict__ resid,
    u16* __restrict__ outb, float* __restrict__ outf, int N)
{
  int e = (blockIdx.x * 256 + threadIdx.x) * 8;
  U128 a = *(const U128*)(p0 + e);
  U128 c = *(const U128*)(p1 + e);
  float v[8];
#pragma unroll
  for (int k = 0; k < 4; k++) {
    v[2*k]   = bf2f((u16)a.x[k]) + bf2f((u16)c.x[k]);
    v[2*k+1] = bf2f((u16)(a.x[k] >> 16)) + bf2f((u16)(c.x[k] >> 16));
  }
  if constexpr (NS == 4) {
    U128 d2 = *(const U128*)(p2 + e);
    U128 d3 = *(const U128*)(p3 + e);
#pragma unroll
    for (int k = 0; k < 4; k++) {
      v[2*k]   += bf2f((u16)d2.x[k]) + bf2f((u16)d3.x[k]);
      v[2*k+1] += bf2f((u16)(d2.x[k] >> 16)) + bf2f((u16)(d3.x[k] >> 16));
    }
  }
  if constexpr (EPI == 2) {
    F128 r0 = *(const F128*)(resid + e);
    F128 r1 = *(const F128*)(resid + e + 4);
    int col = e % N;
    F128 o0, o1;
#pragma unroll
    for (int j = 0; j < 4; j++) {
      float b0 = (bias != nullptr) ? bias[col + j] : 0.0f;
      float b1 = (bias != nullptr) ? bias[col + 4 + j] : 0.0f;
      o0.f[j] = v[j] + b0 + r0.f[j];
      o1.f[j] = v[4 + j] + b1 + r1.f[j];
    }
    *(F128*)(outf + e) = o0;
    *(F128*)(outf + e + 4) = o1;
  } else {
    U128 o;
#pragma unroll
    for (int k = 0; k < 4; k++)
      o.x[k] = (u32)f2bf(v[2*k]) | ((u32)f2bf(v[2*k+1]) << 16);
    *(U128*)(outb + e) = o;
  }
}

// ---------------- extract V from heads into Vt[bh][d][j] --------------------
__global__ __launch_bounds__(256) void extract_vt(
    const u16* __restrict__ heads, u16* __restrict__ Vt)
{
  __shared__ u16 t[64][72];
  int jt = blockIdx.x;           // j tile (0..31)
  int bh = blockIdx.y;           // 0..31
  int b = bh >> 4, h = bh & 15;
  int tid = threadIdx.x;
  int row = tid >> 2;
  int cc = (tid & 3) * 16;
#pragma unroll
  for (int i = 0; i < 2; i++)
    *(U128*)&t[row][cc + i * 8] =
        *(const U128*)&heads[(size_t)((jt * 64 + row) * 2 + b) * 3072 + 2048 + h * 64 + cc + i * 8];
  __syncthreads();
  int jc = tid & 63, dr = tid >> 6;
#pragma unroll
  for (int i = 0; i < 16; i++) {
    int d = dr + i * 4;
    Vt[((size_t)bh * 64 + d) * 2048 + jt * 64 + jc] = t[jc][d];
  }
}

// ---------------- fused rel-attention (flash-style) ------------------------
// VERBATIM R11 kernel (70.4us, reproduced 6x). Do not touch: rt[] arrays
// trigger PromoteAlloca->LDS; inline-asm cvt_pk defeats scheduling; 20-shfl
// variant measured noise-neutral (R17).
__global__ __launch_bounds__(256, 2) void attn_fwd(
    const u16* __restrict__ heads, const u16* __restrict__ rk,
    const u16* __restrict__ Vt, const float* __restrict__ rwb,
    const float* __restrict__ rrb, u16* __restrict__ attnout)
{
  // layout (u16): buf b at b*16384: K @+0 (4096), V @+4096 (4096), R @+8192 (8192)
  // Ps @32768 (64x72). Q overlay @0 during init (Qw 64x72, Qr at +4608).
  __shared__ u16 lds[37376];

  int tid = threadIdx.x, lane = tid & 63, wid = tid >> 6;
  int bh = blockIdx.x;                  // bh%8 -> XCD: blocks sharing K/V co-locate
  int y = (int)blockIdx.y;
  int xt = (y < 8) ? y : 23 - y;        // CU pairing: work(y)+work(y+8) = 49 tiles
  int i0 = xt * 64;
  int b = bh >> 4, h = bh & 15;
  const float SCL = 0.18033688f;        // 0.125 * log2(e)

  u16* Ps = lds + 32768;
  u16* Qw = lds;                        // overlay during init
  u16* Qr = lds + 4608;

  // ---- Q staging (overlay; f32 bias add, bf16 store) ----
  for (int c = tid; c < 512; c += 256) {
    int row = c >> 3, c8 = (c & 7) * 8;
    union { U128 v; u16 h[8]; } in, ow, orr;
    in.v = *(const U128*)&heads[(size_t)((1024 + i0 + row) * 2 + b) * 3072 + h * 64 + c8];
#pragma unroll
    for (int j = 0; j < 8; j++) {
      float q = bf2f(in.h[j]);
      ow.h[j]  = f2bf(q + rwb[h * 64 + c8 + j]);
      orr.h[j] = f2bf(q + rrb[h * 64 + c8 + j]);
    }
    *(U128*)&Qw[row * 72 + c8] = ow.v;
    *(U128*)&Qr[row * 72 + c8] = orr.v;
  }
  __syncthreads();

  bf16x8 qwf[2], qrf[2];
  int qrow = wid * 16 + (lane & 15);
#pragma unroll
  for (int kc = 0; kc < 2; kc++) {
    qwf[kc] = *(const bf16x8*)&Qw[qrow * 72 + kc * 32 + (lane >> 4) * 8];
    qrf[kc] = *(const bf16x8*)&Qr[qrow * 72 + kc * 32 + (lane >> 4) * 8];
  }
  __syncthreads();                 // overlay reads done before gload overwrites

  // ---- staging (global_load_lds, source-side XOR swizzle) ----
  const int srow = lane >> 3;                    // row within 8-row group
  const int scol = 8 * ((lane & 7) ^ srow);      // pre-swizzled source col (u16)

  auto stage = [&](int buf, int t) {
    int j0 = t * 64;
    u16* base = lds + buf * 16384;
#pragma unroll
    for (int i = 0; i < 2; i++) {               // K: rows g8*8+srow
      int g8 = wid * 2 + i;
      int jr = j0 + g8 * 8 + srow;
      gload16(heads + (size_t)(jr * 2 + b) * 3072 + 1024 + h * 64 + scol,
              base + g8 * 512);
    }
#pragma unroll
    for (int i = 0; i < 2; i++) {               // V^T: rows = d
      int g8 = wid * 2 + i;
      int dr = g8 * 8 + srow;
      gload16(Vt + ((size_t)bh * 64 + dr) * 2048 + j0 + scol,
              base + 4096 + g8 * 512);
    }
    int rbase = 960 + j0 - i0;                  // R band (clamped rows masked)
#pragma unroll
    for (int i = 0; i < 4; i++) {
      int g8 = wid * 4 + i;
      int rr = rbase + g8 * 8 + srow;
      rr = rr < 0 ? 0 : (rr > 2047 ? 2047 : rr);
      gload16(rk + (size_t)rr * 1024 + h * 64 + scol,
              base + 8192 + g8 * 512);
    }
  };

  stage(0, 0);
  __syncthreads();                 // tile 0 staged

  float mrow[4], plrow[4];
  f32x4 o[4] = {};
  f32x4 bd[5];
#pragma unroll
  for (int r = 0; r < 4; r++) { mrow[r] = -1e30f; plrow[r] = 0.0f; }

  int nt = i0 / 64 + 17;           // covers j <= i0+63+1024
  const int roffw = 48 - wid * 16;
  const int g = lane >> 4, cc = lane & 15;
  const int rswz = 8 * (lane & 7); // read-side XOR (row&7 == lane&7 for all frags)

  for (int t = 0; t < nt; t++) {
    const u16* base = lds + (t & 1) * 16384;
    if (t + 1 < nt) stage((t + 1) & 1, t + 1);  // overlaps compute below

    const u16* Kb = base;
    const u16* Vb = base + 4096;
    const u16* Rb = base + 8192;

    // AC = Qw.K^T ; BD band frags (fb=0 carried from prev tile, d-window +64)
    f32x4 sAC[4] = {};
    if (t == 0) bd[0] = (f32x4){0.f, 0.f, 0.f, 0.f};
#pragma unroll
    for (int fb = 1; fb < 5; fb++) bd[fb] = (f32x4){0.f, 0.f, 0.f, 0.f};
    __builtin_amdgcn_s_setprio(1);
#pragma unroll
    for (int kc = 0; kc < 2; kc++) {
      int cb = (kc * 32 + g * 8) ^ rswz;
#pragma unroll
      for (int fj = 0; fj < 4; fj++) {
        bf16x8 kf = *(const bf16x8*)&Kb[(fj * 16 + (lane & 15)) * 64 + cb];
        sAC[fj] = MF(qwf[kc], kf, sAC[fj]);
      }
      if (t == 0) {
        bf16x8 rf = *(const bf16x8*)&Rb[(roffw + (lane & 15)) * 64 + cb];
        bd[0] = MF(qrf[kc], rf, bd[0]);
      }
#pragma unroll
      for (int fb = 1; fb < 5; fb++) {
        bf16x8 rf = *(const bf16x8*)&Rb[(roffw + fb * 16 + (lane & 15)) * 64 + cb];
        bd[fb] = MF(qrf[kc], rf, bd[fb]);
      }
    }
    __builtin_amdgcn_s_setprio(0);

    // merge AC + diagonal-gathered BD (log2 domain)
    float p[4][4];
#pragma unroll
    for (int fj = 0; fj < 4; fj++)
#pragma unroll
      for (int r = 0; r < 4; r++) {
        int sh_ = 15 - 4 * g - r;                    // uniform per (quarter, r)
        int src = (lane & 48) | ((lane + sh_) & 15);
        float lo = __shfl(bd[fj][r], src);
        float hi = __shfl(bd[fj + 1][r], src);
        float bdv = (cc + sh_ < 16) ? lo : hi;
        p[fj][r] = (sAC[fj][r] + bdv) * SCL;
      }
    bd[0] = bd[4];                 // carry: next tile's fb=0 window

    if (t == nt - 1) {             // only the last tile has masked entries
#pragma unroll
      for (int fj = 0; fj < 4; fj++)
#pragma unroll
        for (int r = 0; r < 4; r++)
          if (fj * 16 + cc > 16 * wid + 4 * g + r) p[fj][r] = -1e30f;
    }

    float tmax[4];
#pragma unroll
    for (int r = 0; r < 4; r++)
      tmax[r] = fmaxf(fmaxf(p[0][r], p[1][r]), fmaxf(p[2][r], p[3][r]));

    bool ok = true;
#pragma unroll
    for (int r = 0; r < 4; r++) ok &= (tmax[r] <= mrow[r] + 12.0f);
    if (!__all(ok)) {              // rare: true max moved too far -> rescale
#pragma unroll
      for (int off = 1; off < 16; off <<= 1)
#pragma unroll
        for (int r = 0; r < 4; r++)
          tmax[r] = fmaxf(tmax[r], __shfl_xor(tmax[r], off));
#pragma unroll
      for (int r = 0; r < 4; r++) {
        float mn = fmaxf(mrow[r], tmax[r]);
        float ms = exp2f(mrow[r] - mn);
        mrow[r] = mn;
        plrow[r] *= ms;
#pragma unroll
        for (int fd = 0; fd < 4; fd++) o[fd][r] *= ms;
      }
    }

    // P = 2^(p-m) (bounded by 2^12), per-lane l partial, P -> LDS
#pragma unroll
    for (int fj = 0; fj < 4; fj++)
#pragma unroll
      for (int r = 0; r < 4; r++) {
        float e = exp2f(p[fj][r] - mrow[r]);
        plrow[r] += e;
        Ps[(wid * 16 + (lane >> 4) * 4 + r) * 72 + fj * 16 + (lane & 15)] = f2bf(e);
      }
    __builtin_amdgcn_s_setprio(1);
#pragma unroll
    for (int kc = 0; kc < 2; kc++) {
      bf16x8 pf = *(const bf16x8*)&Ps[(wid * 16 + (lane & 15)) * 72 + kc * 32 + g * 8];
      int cb = (kc * 32 + g * 8) ^ rswz;
#pragma unroll
      for (int fd = 0; fd < 4; fd++) {
        bf16x8 vf = *(const bf16x8*)&Vb[(fd * 16 + (lane & 15)) * 64 + cb];
        o[fd] = MF(pf, vf, o[fd]);
      }
    }
    __builtin_amdgcn_s_setprio(0);

    __syncthreads();               // drains stage(t+1) + protects buf reuse
  }

  // epilogue: single deferred l reduction (16-lane groups), then divide
#pragma unroll
  for (int off = 1; off < 16; off <<= 1)
#pragma unroll
    for (int r = 0; r < 4; r++)
      plrow[r] += __shfl_xor(plrow[r], off);
#pragma unroll
  for (int fd = 0; fd < 4; fd++)
#pragma unroll
    for (int r = 0; r < 4; r++) {
      int ii2 = (lane >> 4) * 4 + r;
      int row = (i0 + wid * 16 + ii2) * 2 + b;
      attnout[(size_t)row * 1024 + h * 64 + fd * 16 + (lane & 15)] = f2bf(o[fd][r] / plrow[r]);
    }
}

// ---------------------------------------------------------------------------
extern "C" void kernel_launch(void* const* d_in, const int* in_sizes, int n_in,
                              void* d_out, int out_size, void* d_ws, size_t ws_size,
                              hipStream_t stream)
{
  const float* input_ = (const float*)d_in[0];
  const float* mems   = (const float*)d_in[1];
  const float* pos    = (const float*)d_in[2];
  // d_in[3] = mask_tgt: analytic (j > i + 1024), never read
  const float* ln1g = (const float*)d_in[4];
  const float* ln1b = (const float*)d_in[5];
  const float* qkvw = (const float*)d_in[6];
  const float* qkvb = (const float*)d_in[7];
  const float* rw   = (const float*)d_in[8];
  const float* rwb  = (const float*)d_in[9];
  const float* rrb  = (const float*)d_in[10];
  const float* ow   = (const float*)d_in[11];
  const float* ln2g = (const float*)d_in[12];
  const float* ln2b = (const float*)d_in[13];
  const float* fw1  = (const float*)d_in[14];
  const float* fb1  = (const float*)d_in[15];
  const float* fw2  = (const float*)d_in[16];
  const float* fb2  = (const float*)d_in[17];
  float* out = (float*)d_out;

  char* w = (char*)d_ws;
  u16* WT_QKV = (u16*)(w + 0);          // [3072,1024] bf16   6291456
  u16* WT_R   = (u16*)(w + 6291456);    // [1024,1024]        2097152
  u16* WT_O   = (u16*)(w + 8388608);    // [1024,1024]        2097152
  u16* WT_F1  = (u16*)(w + 10485760);   // [4096,1024]        8388608
  u16* WT_F2  = (u16*)(w + 18874368);   // [1024,4096]        8388608
  u16* POSB   = (u16*)(w + 27262976);   // [2048,1024]        4194304
  u16* ATTN   = POSB;                   // alias: POSB dead after fused QKV+rk
  u16* CATLN  = (u16*)(w + 31457280);   // [4096,1024]        8388608
  u16* HEADS  = (u16*)(w + 39845888);   // [4096,3072]        25165824
  u16* H1     = HEADS;                  // alias: heads dead when F1 gemm runs
  float* X    = (float*)(w + 56623104); // [2048,1024] f32    8388608 (heads tail; live after attn)
  u16* RK     = (u16*)(w + 65011712);   // [2048,1024]        4194304
  u16* VT     = (u16*)(w + 69206016);   // [2,16,64,2048]     8388608
  u16* YN     = VT;                     // alias: VT dead after attention

  // bf16 split-K partials (each 2048x1024 u16 = 4194304 B) in dead regions
  u16* OWP0 = (u16*)(w + 39845888);     // = HEADS (dead after attn)
  u16* OWP1 = (u16*)(w + 44040192);
  u16* OWP2 = (u16*)(w + 48234496);
  u16* OWP3 = (u16*)(w + 52428800);     // ends at 56623104 = X (ln_fuse reads before F1 writes H1)
  u16* F2P0 = (u16*)(w + 0);            // = WT_QKV head (dead)
  u16* F2P1 = (u16*)(w + 10485760);     // = WT_F1 (dead after f1 gemm)
  u16* F2P2 = (u16*)(w + 31457280);     // = CATLN (dead)
  u16* F2P3 = (u16*)(w + 65011712);     // = RK (dead after attn)

  dim3 blk(256);

  // fused weight prep + LN1: 5 transposes + pos cvt + 4096 LN rows, ONE launch
  prep_weights<<<dim3(9472), blk, 0, stream>>>(
      qkvw, rw, ow, fw1, fw2, pos, mems, input_, ln1g, ln1b,
      WT_QKV, WT_R, WT_O, WT_F1, WT_F2, POSB, CATLN);

  // fused: heads = catln @ qkv_w + qkv_b (live blocks only) AND rk = pos @ r_w
  gemm_bt<0, 1, 2><<<dim3(768), blk, 0, stream>>>(
      CATLN, WT_QKV, HEADS, qkvb, POSB, WT_R, RK, nullptr, 4096, 3072, 1024);

  extract_vt<<<dim3(32, 32), blk, 0, stream>>>(HEADS, VT);
  attn_fwd<<<dim3(32, 16), blk, 0, stream>>>(HEADS, RK, VT, rwb, rrb, ATTN);

  // X = input + attn @ o_w  (split-K 4) ; YN = LN(X) fused into the reduce
  gemm_bt<0, 4><<<dim3(16, 8, 4), blk, 0, stream>>>(
      ATTN, WT_O, nullptr, nullptr, OWP0, OWP1, OWP2, OWP3, 2048, 1024, 1024);
  ln_fuse<<<dim3(2048), blk, 0, stream>>>(
      OWP0, OWP1, OWP2, OWP3, input_, ln2g, ln2b, X, YN);

  // FFN: out = X + relu(LN(X) @ w1 + b1) @ w2 + b2
  gemm_bt<1, 1><<<dim3(16, 32), blk, 0, stream>>>(
      YN, WT_F1, H1, fb1, nullptr, nullptr, nullptr, nullptr, 2048, 4096, 1024);
  gemm_bt<0, 4><<<dim3(16, 8, 4), blk, 0, stream>>>(
      H1, WT_F2, nullptr, nullptr, F2P0, F2P1, F2P2, F2P3, 2048, 1024, 4096);
  reduce_splitb<4, 2><<<dim3(1024), blk, 0, stream>>>(
      F2P0, F2P1, F2P2, F2P3, fb2, X, nullptr, out, 1024);
}